// Round 5
// baseline (1606.742 us; speedup 1.0000x reference)
//
#include <hip/hip_runtime.h>
#include <hip/hip_bf16.h>
#include <stdint.h>

#define S_LEN 2048
#define DMODEL 512
#define NH 8
#define DH 64
#define TOPK 32
#define LO_SCALE 4096.0f
#define INV_LO (1.0f/4096.0f)

typedef _Float16 f16;
typedef f16 half8 __attribute__((ext_vector_type(8)));
typedef f16 half4 __attribute__((ext_vector_type(4)));
typedef float floatx4 __attribute__((ext_vector_type(4)));
typedef float f32x4 __attribute__((ext_vector_type(4)));
typedef unsigned long long u64k;

#define AS1 __attribute__((address_space(1)))
#define AS3 __attribute__((address_space(3)))

__device__ __forceinline__ void gl_lds16(const void* g, void* l) {
    __builtin_amdgcn_global_load_lds((const AS1 void*)g, (AS3 void*)l, 16, 0, 0);
}
__device__ __forceinline__ void lds_fence() {
    asm volatile("s_waitcnt lgkmcnt(0)" ::: "memory");
}

// key = sortable(value) in bits [47:16], (0xFFFF - idx) in [15:0]
// -> u64 compare == (value desc, idx asc), identical tie-break to the
// previously passing packed-key scheme.
__device__ __forceinline__ u64k make_key(float f, int idx) {
    unsigned u = __float_as_uint(f);
    unsigned sv = u ^ ((unsigned)(((int)u) >> 31) | 0x80000000u);
    return ((u64k)sv << 16) | (u64k)(0xFFFFu - (unsigned)idx);
}

// ---------------------------------------------------------------------------
// Merged Q+K projection, fp32 vector GEMM.  SELECTION-CRITICAL: per-output
// fma order k=0..511 ascending, identical staging values -> BIT-IDENTICAL.
// 128x128 tile (grid 512 = 2 blocks/CU) with conflict-free grouped-4
// fragment mapping.
// ---------------------------------------------------------------------------
__global__ __launch_bounds__(256)
void qkproj(const float* __restrict__ Xq, const float* __restrict__ Xk,
            const float* __restrict__ Wq_, const float* __restrict__ Wk_,
            const float* __restrict__ bq_, const float* __restrict__ bk_,
            float* __restrict__ outQ, float* __restrict__ outK)
{
    __shared__ float As[32][132];   // [k][m]
    __shared__ float Bs[32][132];   // [k][n]
    const float* X    = blockIdx.z ? Xk  : Xq;
    const float* W    = blockIdx.z ? Wk_ : Wq_;
    const float* bias = blockIdx.z ? bk_ : bq_;
    float* out        = blockIdx.z ? outK : outQ;
    const int tid = threadIdx.x;
    const int tx = tid & 15;        // n: cols tx*4 + h*64, h=0..1
    const int ty = tid >> 4;        // m: rows ty*4 + g*64, g=0..1
    const int m0 = blockIdx.y * 128;
    const int n0 = blockIdx.x * 128;

    float acc[8][8];
#pragma unroll
    for (int i = 0; i < 8; ++i)
#pragma unroll
        for (int j = 0; j < 8; ++j) acc[i][j] = 0.f;

    f32x4 pa[4], pb[4];
#pragma unroll
    for (int u = 0; u < 4; ++u) {
        int id = tid + u * 256;
        pa[u] = *(const f32x4*)(X + (size_t)(m0 + (id >> 3)) * 512 + (id & 7) * 4);
        pb[u] = *(const f32x4*)(W + (size_t)(id >> 5) * 512 + n0 + (id & 31) * 4);
    }

    for (int k0 = 0; k0 < 512; k0 += 32) {
#pragma unroll
        for (int u = 0; u < 4; ++u) {
            int id = tid + u * 256;
            int r = id >> 3, c4 = (id & 7) * 4;
            As[c4 + 0][r] = pa[u].x; As[c4 + 1][r] = pa[u].y;
            As[c4 + 2][r] = pa[u].z; As[c4 + 3][r] = pa[u].w;
            int rb = id >> 5, cb = (id & 31) * 4;
            *(f32x4*)&Bs[rb][cb] = pb[u];
        }
        __syncthreads();
        if (k0 < 480) {
            int kn = k0 + 32;
#pragma unroll
            for (int u = 0; u < 4; ++u) {
                int id = tid + u * 256;
                pa[u] = *(const f32x4*)(X + (size_t)(m0 + (id >> 3)) * 512 + kn + (id & 7) * 4);
                pb[u] = *(const f32x4*)(W + (size_t)(kn + (id >> 5)) * 512 + n0 + (id & 31) * 4);
            }
        }
#pragma unroll 8
        for (int kk = 0; kk < 32; ++kk) {
            float a[8], b[8];
            *(f32x4*)&a[0] = *(const f32x4*)&As[kk][ty * 4];
            *(f32x4*)&a[4] = *(const f32x4*)&As[kk][64 + ty * 4];
            *(f32x4*)&b[0] = *(const f32x4*)&Bs[kk][tx * 4];
            *(f32x4*)&b[4] = *(const f32x4*)&Bs[kk][64 + tx * 4];
#pragma unroll
            for (int i = 0; i < 8; ++i)
#pragma unroll
                for (int j = 0; j < 8; ++j)
                    acc[i][j] = fmaf(a[i], b[j], acc[i][j]);
        }
        __syncthreads();
    }

    float bb[8];
    *(f32x4*)&bb[0] = *(const f32x4*)(bias + n0 + tx * 4);
    *(f32x4*)&bb[4] = *(const f32x4*)(bias + n0 + 64 + tx * 4);

#pragma unroll
    for (int i = 0; i < 8; ++i) {
        int r = m0 + ((i >> 2) << 6) + ty * 4 + (i & 3);
        int b_ = r >> 11, s = r & 2047;
#pragma unroll
        for (int h = 0; h < 2; ++h) {
            int c = n0 + h * 64 + tx * 4;
            f32x4 w = {acc[i][h * 4 + 0] + bb[h * 4 + 0],
                       acc[i][h * 4 + 1] + bb[h * 4 + 1],
                       acc[i][h * 4 + 2] + bb[h * 4 + 2],
                       acc[i][h * 4 + 3] + bb[h * 4 + 3]};
            int hd = c >> 6, d = c & 63;
            float* p = out + (((size_t)(b_ * NH + hd) * S_LEN) + s) * DH + d;
            *(f32x4*)p = w;
        }
    }
}

// ---------------------------------------------------------------------------
// FUSED fp32 logits + exact top-32.  SELECTION-CRITICAL invariants:
//  * logits bits: per output, fma chain (d-chunk 0 asc kk, chunk 1 asc kk)
//    with A staged as Q*0.125 -- IDENTICAL ops/order to the passing kernel.
//  * winner set: exact top-32 by key (value desc, idx asc), online in
//    registers: 2 sorted keys/lane per 16-lane group (R3/R4's HW-verified
//    seed + bitonic-32 + bounded shuffle-insert network, unchanged).
// R5 REGISTER FIX: R4's 8-rows/thread held 16 u64 keys/thread; at
// VGPR_Count=88 the compiler demoted keys+insert temps to scratch (VALU
// time 5x FMA floor).  Re-tiled to 4 rows x 16 cols/thread (q-tile 64,
// panel 256, 8 panels): keys = 8 u64 = 16 VGPR -> whole working set
// ~145 VGPR, register-resident.  Grid 1024 blocks (2x parallelism),
// 16 barrier phases (half), K-panel register prefetch restored.
// Output format unchanged: 32 sorted keys in first 256 B of own w row.
// ---------------------------------------------------------------------------
__global__ __launch_bounds__(256)
void logits_topk(const float* __restrict__ Qh, const float* __restrict__ Kh,
                 float* __restrict__ wbuf)
{
    __shared__ float As[2][32][68];    // both d-chunks of the 64-row Q tile
    __shared__ float Bs[32][260];      // one d-chunk of a 256-row K panel, transposed
    const int tid = threadIdx.x;
    const int lig = tid & 15;                 // lane in 16-lane group
    const int ty  = tid >> 4;                 // row-group id (0..15)
    const int gsh = ((tid & 63) >> 4) << 4;   // group's bit-shift in wave ballots
    const int bh = blockIdx.y;
    const int q0 = blockIdx.x * 64;
    const float* Ab = Qh + (size_t)bh * S_LEN * DH;
    const float* Bb = Kh + (size_t)bh * S_LEN * DH;

    float acc[4][16];
#pragma unroll
    for (int i = 0; i < 4; ++i)
#pragma unroll
        for (int j = 0; j < 16; ++j) acc[i][j] = 0.f;

    u64k key0[4], key1[4];                    // per row: ranks 2*lig, 2*lig+1
#pragma unroll
    for (int i = 0; i < 4; ++i) { key0[i] = 0; key1[i] = 0; }

    // stage the Q tile once: As[ch][kk][r] = Q[q0+r][ch*32+kk] * 0.125
    // (identical values to the passing kernel's staging)
#pragma unroll
    for (int u = 0; u < 4; ++u) {
        int id = tid + u * 256;
        int r = id >> 4, c4 = (id & 15) * 4;
        int ch = c4 >> 5, cl = c4 & 31;
        f32x4 x = *(const f32x4*)(Ab + (size_t)(q0 + r) * DH + c4);
        As[ch][cl + 0][r] = x.x * 0.125f;
        As[ch][cl + 1][r] = x.y * 0.125f;
        As[ch][cl + 2][r] = x.z * 0.125f;
        As[ch][cl + 3][r] = x.w * 0.125f;
    }

    // register prefetch of K panel 0, chunk 0
    f32x4 kb[8];
#pragma unroll
    for (int u = 0; u < 8; ++u) {
        int id = tid + u * 256;
        int r = id >> 3, c4 = (id & 7) * 4;
        kb[u] = *(const f32x4*)(Bb + (size_t)r * DH + c4);
    }

#pragma unroll 1
    for (int kp = 0; kp < 8; ++kp) {
#pragma unroll
        for (int ch = 0; ch < 2; ++ch) {
            __syncthreads();      // previous phase's Bs readers done
#pragma unroll
            for (int u = 0; u < 8; ++u) {
                int id = tid + u * 256;
                int r = id >> 3, c4 = (id & 7) * 4;
                Bs[c4 + 0][r] = kb[u].x; Bs[c4 + 1][r] = kb[u].y;
                Bs[c4 + 2][r] = kb[u].z; Bs[c4 + 3][r] = kb[u].w;
            }
            __syncthreads();      // Bs (and, first time, As) visible
            // prefetch next chunk (hidden under the kk loop)
            {
                int nkp = ch ? kp + 1 : kp;
                int nch = ch ? 0 : 1;
                if (nkp < 8) {
#pragma unroll
                    for (int u = 0; u < 8; ++u) {
                        int id = tid + u * 256;
                        int r = id >> 3, c4 = (id & 7) * 4;
                        kb[u] = *(const f32x4*)(Bb + (size_t)(nkp * 256 + r) * DH + nch * 32 + c4);
                    }
                }
            }
#pragma unroll 8
            for (int kk = 0; kk < 32; ++kk) {
                float a[4], b[16];
                *(f32x4*)&a[0] = *(const f32x4*)&As[ch][kk][ty * 4];
#pragma unroll
                for (int h = 0; h < 4; ++h)
                    *(f32x4*)&b[h * 4] = *(const f32x4*)&Bs[kk][lig * 4 + h * 64];
#pragma unroll
                for (int i = 0; i < 4; ++i)
#pragma unroll
                    for (int j = 0; j < 16; ++j)
                        acc[i][j] = fmaf(a[i], b[j], acc[i][j]);
            }
        }

        // ---- exact online top-32 update (registers + shuffles only) -----
        // col of acc[i][j] = kp*256 + (j>>2)*64 + lig*4 + (j&3)
#pragma unroll
        for (int i = 0; i < 4; ++i) {
            int j0 = -1, j1 = -1;
            if (kp == 0) {
                // seed: this lane's top-2 of its 16 values (exact key order)
                u64k t0 = 0, t1 = 0;
#pragma unroll
                for (int j = 0; j < 16; ++j) {
                    u64k kj = make_key(acc[i][j], ((j >> 2) << 6) + (lig << 2) + (j & 3));
                    if (kj > t0)      { t1 = t0; j1 = j0; t0 = kj; j0 = j; }
                    else if (kj > t1) { t1 = kj; j1 = j; }
                }
                key0[i] = t0; key1[i] = t1;
                // bitonic sort-32 descending across the group (2 elems/lane)
#pragma unroll
                for (int s = 2; s <= 32; s <<= 1) {
#pragma unroll
                    for (int d = s >> 1; d >= 1; d >>= 1) {
                        int e0 = 2 * lig;
                        if (d == 1) {
                            bool descB = ((e0 & s) == 0);
                            u64k mx = key0[i] > key1[i] ? key0[i] : key1[i];
                            u64k mn = key0[i] > key1[i] ? key1[i] : key0[i];
                            key0[i] = descB ? mx : mn;
                            key1[i] = descB ? mn : mx;
                        } else {
                            bool descB = ((e0 & s) == 0);
                            bool amS   = ((e0 & d) == 0);
                            bool wantMax = (descB == amS);
                            u64k p0 = __shfl_xor(key0[i], d >> 1, 16);
                            u64k p1 = __shfl_xor(key1[i], d >> 1, 16);
                            key0[i] = wantMax ? (key0[i] > p0 ? key0[i] : p0)
                                              : (key0[i] > p0 ? p0 : key0[i]);
                            key1[i] = wantMax ? (key1[i] > p1 ? key1[i] : p1)
                                              : (key1[i] > p1 ? p1 : key1[i]);
                        }
                    }
                }
            }
            // candidates strictly above current rank-31 (exclude panel-0 seeds)
            u64k bot0 = __shfl(key1[i], 15, 16);
            unsigned pend = 0;
#pragma unroll
            for (int j = 0; j < 16; ++j) {
                u64k kj = make_key(acc[i][j], kp * 256 + ((j >> 2) << 6) + (lig << 2) + (j & 3));
                if (kj > bot0 && j != j0 && j != j1) pend |= (1u << j);
            }
            // bounded: each iteration consumes exactly one pending bit of
            // the group's first pending lane; <=256 candidates/panel.
            for (int it = 0; it < 300; ++it) {
                unsigned long long wb = __ballot(pend != 0);
                unsigned gm = (unsigned)((wb >> gsh) & 0xFFFFull);
                if (!gm) break;
                int src = __ffs((int)gm) - 1;
                int myj = __ffs((int)pend) - 1;
                float mv = acc[i][0];
#pragma unroll
                for (int j = 1; j < 16; ++j) if (myj == j) mv = acc[i][j];
                int jj = myj < 0 ? 0 : myj;
                u64k ck = make_key(mv, kp * 256 + ((jj >> 2) << 6) + (lig << 2) + (jj & 3));
                ck = __shfl(ck, src, 16);
                if (lig == src) pend &= pend - 1;     // consume (progress guaranteed)
                u64k bt = __shfl(key1[i], 15, 16);
                if (ck <= bt) continue;               // stale candidate, exact check
                unsigned long long b0 = __ballot(key0[i] > ck);
                unsigned long long b1 = __ballot(key1[i] > ck);
                int pos = __popcll((b0 >> gsh) & 0xFFFFull)
                        + __popcll((b1 >> gsh) & 0xFFFFull);
                u64k up = __shfl_up(key1[i], 1, 16);  // prev lane's rank 2*lig-1
                int e0 = 2 * lig, e1 = e0 + 1;
                u64k nk0 = (e0 < pos) ? key0[i] : ((e0 == pos) ? ck : up);
                u64k nk1 = (e1 < pos) ? key1[i] : ((e1 == pos) ? ck : key0[i]);
                key0[i] = nk0; key1[i] = nk1;         // old rank-31 drops
            }
        }

        // reset accumulators for the next panel (keys hold the result)
#pragma unroll
        for (int i = 0; i < 4; ++i)
#pragma unroll
            for (int j = 0; j < 16; ++j) acc[i][j] = 0.f;
    }

    // ---- dump winners: 32 sorted keys into the row's own w row ----------
#pragma unroll
    for (int i = 0; i < 4; ++i) {
        int r = q0 + ty * 4 + i;
        float* wr = wbuf + ((size_t)bh * S_LEN + r) * S_LEN;
        *(u64k*)(wr + (lig << 2))     = key0[i];   // slot 2*lig
        *(u64k*)(wr + (lig << 2) + 2) = key1[i];   // slot 2*lig+1
    }
}

// ---------------------------------------------------------------------------
// Weight transpose + fp16 hi/lo split for Wv (z=0) and Wo (z=1) only.
// ---------------------------------------------------------------------------
__global__ __launch_bounds__(256)
void wsplit2(const float* __restrict__ W0, const float* __restrict__ W1,
             f16* __restrict__ planes)
{
    __shared__ float tile[32][33];
    const float* W = blockIdx.z ? W1 : W0;
    f16* Th = planes + (size_t)blockIdx.z * 524288;
    f16* Tl = Th + 262144;
    const int bx = blockIdx.x * 32;
    const int by = blockIdx.y * 32;
    const int lx = threadIdx.x & 31, ly = threadIdx.x >> 5;
#pragma unroll
    for (int r = ly; r < 32; r += 8)
        tile[r][lx] = W[(size_t)(by + r) * 512 + bx + lx];
    __syncthreads();
#pragma unroll
    for (int r = ly; r < 32; r += 8) {
        float x = tile[lx][r];              // = W[by+lx][bx+r]
        f16 h = (f16)x;
        f16 l = (f16)((x - (float)h) * LO_SCALE);
        Th[(size_t)(bx + r) * 512 + by + lx] = h;
        Tl[(size_t)(bx + r) * 512 + by + lx] = l;
    }
}

// ---------------------------------------------------------------------------
// Split-fp16 MFMA GEMM, A fp32 (in-kernel split): V projection only
// (selection-irrelevant).  mode 1 = fp32 head-split write.
// ---------------------------------------------------------------------------
__global__ __launch_bounds__(256)
void gemm_x32(const float* __restrict__ X,
              const f16* __restrict__ Bh_, const f16* __restrict__ Bl_,
              const float* __restrict__ bias, float* __restrict__ outF, int mode)
{
    __shared__ f16 sm[16384];
    f16* As_h = sm;       f16* As_l = sm + 4096;
    f16* Bs_h = sm + 8192; f16* Bs_l = sm + 12288;
    const int tid  = threadIdx.x;
    const int lane = tid & 63, wv = tid >> 6;
    const int wm = wv & 1, wn = wv >> 1;
    const int quad = lane >> 4, l15 = lane & 15;
    const int m0 = blockIdx.y * 128, n0 = blockIdx.x * 128;

    floatx4 acc_h[4][4], acc_c[4][4];
    const floatx4 z4 = {0.f, 0.f, 0.f, 0.f};
#pragma unroll
    for (int i = 0; i < 4; ++i)
#pragma unroll
        for (int j = 0; j < 4; ++j) { acc_h[i][j] = z4; acc_c[i][j] = z4; }

    for (int k0 = 0; k0 < 512; k0 += 32) {
        __syncthreads();
#pragma unroll
        for (int c = 0; c < 4; ++c) {
            int r   = c * 32 + (tid >> 3);
            int col = (tid & 7) * 4;
            f32x4 x = *(const f32x4*)(X + (size_t)(m0 + r) * 512 + k0 + col);
            f16 h0 = (f16)x.x, h1 = (f16)x.y, h2 = (f16)x.z, h3 = (f16)x.w;
            half4 hv = {h0, h1, h2, h3};
            half4 lv = {(f16)((x.x - (float)h0) * LO_SCALE),
                        (f16)((x.y - (float)h1) * LO_SCALE),
                        (f16)((x.z - (float)h2) * LO_SCALE),
                        (f16)((x.w - (float)h3) * LO_SCALE)};
            *(half4*)&As_h[r * 32 + col] = hv;
            *(half4*)&As_l[r * 32 + col] = lv;
        }
#pragma unroll
        for (int c = 0; c < 2; ++c) {
            int r    = c * 64 + (wv << 4) + (lane >> 2);
            int ch   = (lane & 3) * 8;
            int lidx = (c * 64 + (wv << 4)) * 32 + lane * 8;
            gl_lds16(Bh_ + (size_t)(n0 + r) * 512 + k0 + ch, &Bs_h[lidx]);
            gl_lds16(Bl_ + (size_t)(n0 + r) * 512 + k0 + ch, &Bs_l[lidx]);
        }
        asm volatile("s_waitcnt vmcnt(0)" ::: "memory");
        __syncthreads();

        half8 bh8[4], bl8[4];
#pragma unroll
        for (int j = 0; j < 4; ++j) {
            int n = wn * 64 + j * 16 + l15;
            bh8[j] = *(const half8*)&Bs_h[n * 32 + quad * 8];
            bl8[j] = *(const half8*)&Bs_l[n * 32 + quad * 8];
        }
#pragma unroll
        for (int i = 0; i < 4; ++i) {
            int m = wm * 64 + i * 16 + l15;
            half8 ah = *(const half8*)&As_h[m * 32 + quad * 8];
            half8 al = *(const half8*)&As_l[m * 32 + quad * 8];
#pragma unroll
            for (int j = 0; j < 4; ++j) {
                acc_h[i][j] = __builtin_amdgcn_mfma_f32_16x16x32_f16(ah, bh8[j], acc_h[i][j], 0, 0, 0);
                acc_c[i][j] = __builtin_amdgcn_mfma_f32_16x16x32_f16(ah, bl8[j], acc_c[i][j], 0, 0, 0);
                acc_c[i][j] = __builtin_amdgcn_mfma_f32_16x16x32_f16(al, bh8[j], acc_c[i][j], 0, 0, 0);
            }
        }
    }

#pragma unroll
    for (int j = 0; j < 4; ++j) {
        int col = n0 + wn * 64 + j * 16 + l15;
        float bv = bias[col];
#pragma unroll
        for (int i = 0; i < 4; ++i) {
            int rbase = m0 + wm * 64 + i * 16 + quad * 4;
#pragma unroll
            for (int rg = 0; rg < 4; ++rg) {
                float r = acc_h[i][j][rg] + acc_c[i][j][rg] * INV_LO + bv;
                int row = rbase + rg;
                if (mode == 2) {
                    outF[(size_t)row * 512 + col] = r;
                } else {
                    int b_ = row >> 11, s = row & 2047, h = col >> 6, d = col & 63;
                    outF[(((size_t)(b_ * NH + h)) * S_LEN + s) * DH + d] = r;
                }
            }
        }
    }
}

// ---------------------------------------------------------------------------
// Split-fp16 MFMA GEMM, both operands pre-split planes [row][k].
// mode 2: out-proj (K=512, C = A@B^T + bias, fp32 [8192][512]).
// ---------------------------------------------------------------------------
__global__ __launch_bounds__(256)
void gemm_x16(const f16* __restrict__ Ah_, const f16* __restrict__ Al_,
              const f16* __restrict__ Bh_, const f16* __restrict__ Bl_,
              const float* __restrict__ bias, float* __restrict__ outF,
              int Ksz, int ldc, int mode)
{
    __shared__ f16 sm[16384];
    f16* As_h = sm;        f16* As_l = sm + 4096;
    f16* Bs_h = sm + 8192; f16* Bs_l = sm + 12288;
    const int tid  = threadIdx.x;
    const int lane = tid & 63, wv = tid >> 6;
    const int wm = wv & 1, wn = wv >> 1;
    const int quad = lane >> 4, l15 = lane & 15;
    const int m0 = blockIdx.y * 128, n0 = blockIdx.x * 128;

    floatx4 acc_h[4][4], acc_c[4][4];
    const floatx4 z4 = {0.f, 0.f, 0.f, 0.f};
#pragma unroll
    for (int i = 0; i < 4; ++i)
#pragma unroll
        for (int j = 0; j < 4; ++j) { acc_h[i][j] = z4; acc_c[i][j] = z4; }

    for (int k0 = 0; k0 < Ksz; k0 += 32) {
        __syncthreads();
#pragma unroll
        for (int c = 0; c < 2; ++c) {
            int r    = c * 64 + (wv << 4) + (lane >> 2);
            int ch   = (lane & 3) * 8;
            int lidx = (c * 64 + (wv << 4)) * 32 + lane * 8;
            gl_lds16(Ah_ + (size_t)(m0 + r) * Ksz + k0 + ch, &As_h[lidx]);
            gl_lds16(Al_ + (size_t)(m0 + r) * Ksz + k0 + ch, &As_l[lidx]);
            gl_lds16(Bh_ + (size_t)(n0 + r) * Ksz + k0 + ch, &Bs_h[lidx]);
            gl_lds16(Bl_ + (size_t)(n0 + r) * Ksz + k0 + ch, &Bs_l[lidx]);
        }
        asm volatile("s_waitcnt vmcnt(0)" ::: "memory");
        __syncthreads();

        half8 bh8[4], bl8[4];
#pragma unroll
        for (int j = 0; j < 4; ++j) {
            int n = wn * 64 + j * 16 + l15;
            bh8[j] = *(const half8*)&Bs_h[n * 32 + quad * 8];
            bl8[j] = *(const half8*)&Bs_l[n * 32 + quad * 8];
        }
#pragma unroll
        for (int i = 0; i < 4; ++i) {
            int m = wm * 64 + i * 16 + l15;
            half8 ah = *(const half8*)&As_h[m * 32 + quad * 8];
            half8 al = *(const half8*)&As_l[m * 32 + quad * 8];
#pragma unroll
            for (int j = 0; j < 4; ++j) {
                acc_h[i][j] = __builtin_amdgcn_mfma_f32_16x16x32_f16(ah, bh8[j], acc_h[i][j], 0, 0, 0);
                acc_c[i][j] = __builtin_amdgcn_mfma_f32_16x16x32_f16(ah, bl8[j], acc_c[i][j], 0, 0, 0);
                acc_c[i][j] = __builtin_amdgcn_mfma_f32_16x16x32_f16(al, bh8[j], acc_c[i][j], 0, 0, 0);
            }
        }
    }

#pragma unroll
    for (int j = 0; j < 4; ++j) {
        int col = n0 + wn * 64 + j * 16 + l15;
        float bv = (mode == 2) ? bias[col] : 0.f;
#pragma unroll
        for (int i = 0; i < 4; ++i) {
            int rbase = m0 + wm * 64 + i * 16 + quad * 4;
#pragma unroll
            for (int rg = 0; rg < 4; ++rg) {
                float r = acc_h[i][j][rg] + acc_c[i][j][rg] * INV_LO;
                int row = rbase + rg;
                outF[(size_t)row * ldc + col] = r + bv;
            }
        }
    }
}

// ---------------------------------------------------------------------------
// Scatter + sparse attention.  One wave per query row.  Reads the row's 32
// pre-ranked winner keys (first 256 B of its own w row, written by
// logits_topk), computes e=exp(v-m) exactly as before (m = rank-0 = row
// max), renormalizes, then zero+scatter+NT-stream of the full w row and the
// 32-term weighted V sum.  No logits re-read, no threshold search.
// ---------------------------------------------------------------------------
__global__ __launch_bounds__(256)
void topk_scatter(float* __restrict__ wbuf, const float* __restrict__ Vh,
                  f16* __restrict__ attH, f16* __restrict__ attL)
{
    __shared__ float wrow[4][2048];
    __shared__ float win_w[4][TOPK];
    __shared__ int   win_i[4][TOPK];

    const int tid  = threadIdx.x;
    const int wv   = tid >> 6;
    const int lane = tid & 63;
    const int row  = blockIdx.x * 4 + wv;       // (b*8+h)*2048 + s
    float* wr = wbuf + (size_t)row * 2048;

    u64k key = 0;
    if (lane < TOPK) key = ((const u64k*)wr)[lane];
    unsigned sv = (unsigned)(key >> 16);
    unsigned fu = (sv & 0x80000000u) ? (sv ^ 0x80000000u) : ~sv;
    float v = __uint_as_float(fu);
    int idx = (int)(0xFFFFu - (unsigned)(key & 0xFFFFull)) & 2047;

    float m = __shfl(v, 0, 64);                 // rank-0 value = row max
    float e = (lane < TOPK) ? __expf(v - m) : 0.f;

    float mysum = e;
#pragma unroll
    for (int off = 32; off > 0; off >>= 1) mysum += __shfl_xor(mysum, off, 64);
    const float rw = 1.f / mysum;

    if (lane < TOPK) { win_w[wv][lane] = e; win_i[wv][lane] = idx; }

    const f32x4 z = {0.f, 0.f, 0.f, 0.f};
#pragma unroll
    for (int t = 0; t < 8; ++t) ((f32x4*)wrow[wv])[t * 64 + lane] = z;
    lds_fence();
    if (lane < TOPK) wrow[wv][win_i[wv][lane]] = win_w[wv][lane] * rw;
    lds_fence();

    // stream the sparse w row out (overwrites the winner-key scratch too)
#pragma unroll
    for (int t = 0; t < 8; ++t)
        __builtin_nontemporal_store(((f32x4*)wrow[wv])[t * 64 + lane],
                                    (f32x4*)(wr + (size_t)(t * 64 + lane) * 4));

    // sparse attention: 32 weighted V rows; lane = head-dim index
    const int bh = row >> 11;
    const float* Vb = Vh + (size_t)bh * S_LEN * DH;
    float acc = 0.f;
#pragma unroll
    for (int j = 0; j < TOPK; ++j) {
        float wj = win_w[wv][j] * rw;
        int   kj = win_i[wv][j];
        acc = fmaf(wj, Vb[(size_t)kj * DH + lane], acc);
    }
    const int b_ = row >> 14;
    const int h  = (row >> 11) & 7;
    const int s  = row & 2047;
    size_t oidx = (((size_t)b_ * S_LEN) + s) * 512 + h * DH + lane;
    f16 hh = (f16)acc;
    attH[oidx] = hh;
    attL[oidx] = (f16)((acc - (float)hh) * LO_SCALE);
}

// ---------------------------------------------------------------------------
extern "C" void kernel_launch(void* const* d_in, const int* in_sizes, int n_in,
                              void* d_out, int out_size, void* d_ws, size_t ws_size,
                              hipStream_t stream) {
    const float* v  = (const float*)d_in[0];
    const float* k  = (const float*)d_in[1];
    const float* q  = (const float*)d_in[2];
    const float* Wq = (const float*)d_in[3];
    const float* bq = (const float*)d_in[4];
    const float* Wk = (const float*)d_in[5];
    const float* bk = (const float*)d_in[6];
    const float* Wv = (const float*)d_in[7];
    const float* bv = (const float*)d_in[8];
    const float* Wo = (const float*)d_in[9];
    const float* bo = (const float*)d_in[10];

    float* out  = (float*)d_out;                    // [4,2048,512]
    float* wout = out + (size_t)4 * S_LEN * 512;    // [4,8,2048,2048] w output

    char* ws = (char*)d_ws;
    float* Vh   = (float*)ws;                       // fp32 [B,H,S,dh], 16 MB
    float* Qh32 = (float*)(ws + 16777216);          // fp32 [B,H,S,dh], 16 MB
    float* Kh32 = (float*)(ws + 33554432);          // fp32 [B,H,S,dh], 16 MB
    f16* WT  = (f16*)(ws + 50331648);               // 4 planes of 512x512, 2 MB
    f16 *WvH = WT,           *WvL = WT + 262144;
    f16 *WoH = WT + 524288,  *WoL = WT + 786432;
    // att planes alias Qh32 (dead after logits_topk): 8 MB + 8 MB
    f16* attH = (f16*)(ws + 16777216);
    f16* attL = (f16*)(ws + 25165824);

    wsplit2<<<dim3(16, 16, 2), 256, 0, stream>>>(Wv, Wo, WT);

    qkproj<<<dim3(4, 64, 2), 256, 0, stream>>>(q, k, Wq, Wk, bq, bk, Qh32, Kh32);
    gemm_x32<<<dim3(4, 64), 256, 0, stream>>>(v, WvH, WvL, bv, Vh, 1);

    logits_topk<<<dim3(32, 32), 256, 0, stream>>>(Qh32, Kh32, wout);

    topk_scatter<<<16384, 256, 0, stream>>>(wout, Vh, attH, attL);

    gemm_x16<<<dim3(4, 64, 1), 256, 0, stream>>>(attH, attL, WoH, WoL, bo, out, 512, 512, 2);
}

// Round 7
// 1269.896 us; speedup vs baseline: 1.2653x; 1.2653x over previous
//
#include <hip/hip_runtime.h>
#include <hip/hip_bf16.h>
#include <stdint.h>

#define S_LEN 2048
#define DMODEL 512
#define NH 8
#define DH 64
#define TOPK 32
#define LO_SCALE 4096.0f
#define INV_LO (1.0f/4096.0f)

typedef _Float16 f16;
typedef f16 half8 __attribute__((ext_vector_type(8)));
typedef f16 half4 __attribute__((ext_vector_type(4)));
typedef float floatx4 __attribute__((ext_vector_type(4)));
typedef float f32x4 __attribute__((ext_vector_type(4)));
typedef unsigned long long u64k;

#define AS1 __attribute__((address_space(1)))
#define AS3 __attribute__((address_space(3)))

__device__ __forceinline__ void gl_lds16(const void* g, void* l) {
    __builtin_amdgcn_global_load_lds((const AS1 void*)g, (AS3 void*)l, 16, 0, 0);
}
__device__ __forceinline__ void lds_fence() {
    asm volatile("s_waitcnt lgkmcnt(0)" ::: "memory");
}

// key = sortable(value) in bits [47:16], (0xFFFF - idx) in [15:0]
// -> u64 compare == (value desc, idx asc), identical tie-break to the
// previously passing packed-key scheme.
__device__ __forceinline__ u64k make_key(float f, int idx) {
    unsigned u = __float_as_uint(f);
    unsigned sv = u ^ ((unsigned)(((int)u) >> 31) | 0x80000000u);
    return ((u64k)sv << 16) | (u64k)(0xFFFFu - (unsigned)idx);
}

// ---------------------------------------------------------------------------
// Merged Q+K projection, fp32 vector GEMM.  SELECTION-CRITICAL: per-output
// fma order k=0..511 ascending, identical staging values -> BIT-IDENTICAL.
// 128x128 tile (grid 512 = 2 blocks/CU) with conflict-free grouped-4
// fragment mapping.
// ---------------------------------------------------------------------------
__global__ __launch_bounds__(256)
void qkproj(const float* __restrict__ Xq, const float* __restrict__ Xk,
            const float* __restrict__ Wq_, const float* __restrict__ Wk_,
            const float* __restrict__ bq_, const float* __restrict__ bk_,
            float* __restrict__ outQ, float* __restrict__ outK)
{
    __shared__ float As[32][132];   // [k][m]
    __shared__ float Bs[32][132];   // [k][n]
    const float* X    = blockIdx.z ? Xk  : Xq;
    const float* W    = blockIdx.z ? Wk_ : Wq_;
    const float* bias = blockIdx.z ? bk_ : bq_;
    float* out        = blockIdx.z ? outK : outQ;
    const int tid = threadIdx.x;
    const int tx = tid & 15;        // n: cols tx*4 + h*64, h=0..1
    const int ty = tid >> 4;        // m: rows ty*4 + g*64, g=0..1
    const int m0 = blockIdx.y * 128;
    const int n0 = blockIdx.x * 128;

    float acc[8][8];
#pragma unroll
    for (int i = 0; i < 8; ++i)
#pragma unroll
        for (int j = 0; j < 8; ++j) acc[i][j] = 0.f;

    f32x4 pa[4], pb[4];
#pragma unroll
    for (int u = 0; u < 4; ++u) {
        int id = tid + u * 256;
        pa[u] = *(const f32x4*)(X + (size_t)(m0 + (id >> 3)) * 512 + (id & 7) * 4);
        pb[u] = *(const f32x4*)(W + (size_t)(id >> 5) * 512 + n0 + (id & 31) * 4);
    }

    for (int k0 = 0; k0 < 512; k0 += 32) {
#pragma unroll
        for (int u = 0; u < 4; ++u) {
            int id = tid + u * 256;
            int r = id >> 3, c4 = (id & 7) * 4;
            As[c4 + 0][r] = pa[u].x; As[c4 + 1][r] = pa[u].y;
            As[c4 + 2][r] = pa[u].z; As[c4 + 3][r] = pa[u].w;
            int rb = id >> 5, cb = (id & 31) * 4;
            *(f32x4*)&Bs[rb][cb] = pb[u];
        }
        __syncthreads();
        if (k0 < 480) {
            int kn = k0 + 32;
#pragma unroll
            for (int u = 0; u < 4; ++u) {
                int id = tid + u * 256;
                pa[u] = *(const f32x4*)(X + (size_t)(m0 + (id >> 3)) * 512 + kn + (id & 7) * 4);
                pb[u] = *(const f32x4*)(W + (size_t)(kn + (id >> 5)) * 512 + n0 + (id & 31) * 4);
            }
        }
#pragma unroll 8
        for (int kk = 0; kk < 32; ++kk) {
            float a[8], b[8];
            *(f32x4*)&a[0] = *(const f32x4*)&As[kk][ty * 4];
            *(f32x4*)&a[4] = *(const f32x4*)&As[kk][64 + ty * 4];
            *(f32x4*)&b[0] = *(const f32x4*)&Bs[kk][tx * 4];
            *(f32x4*)&b[4] = *(const f32x4*)&Bs[kk][64 + tx * 4];
#pragma unroll
            for (int i = 0; i < 8; ++i)
#pragma unroll
                for (int j = 0; j < 8; ++j)
                    acc[i][j] = fmaf(a[i], b[j], acc[i][j]);
        }
        __syncthreads();
    }

    float bb[8];
    *(f32x4*)&bb[0] = *(const f32x4*)(bias + n0 + tx * 4);
    *(f32x4*)&bb[4] = *(const f32x4*)(bias + n0 + 64 + tx * 4);

#pragma unroll
    for (int i = 0; i < 8; ++i) {
        int r = m0 + ((i >> 2) << 6) + ty * 4 + (i & 3);
        int b_ = r >> 11, s = r & 2047;
#pragma unroll
        for (int h = 0; h < 2; ++h) {
            int c = n0 + h * 64 + tx * 4;
            f32x4 w = {acc[i][h * 4 + 0] + bb[h * 4 + 0],
                       acc[i][h * 4 + 1] + bb[h * 4 + 1],
                       acc[i][h * 4 + 2] + bb[h * 4 + 2],
                       acc[i][h * 4 + 3] + bb[h * 4 + 3]};
            int hd = c >> 6, d = c & 63;
            float* p = out + (((size_t)(b_ * NH + hd) * S_LEN) + s) * DH + d;
            *(f32x4*)p = w;
        }
    }
}

// ---------------------------------------------------------------------------
// FUSED fp32 logits + exact top-32.  SELECTION-CRITICAL invariants:
//  * logits bits: per output, fma chain (d-chunk 0 asc kk, chunk 1 asc kk)
//    with A staged as Q*0.125 -- IDENTICAL ops/order to the passing kernel.
//  * winner set: exact top-32 by key (value desc, idx asc).
// Batched merge top-k (R6 design): candidates (key > running 32nd-best)
// append to a per-row LDS slab via ballot prefix (data-parallel); batches
// merge with register bitonic sort-32 + bitonic merge (compile-time
// shfl_xor masks).  Overflow handled exactly via merge-and-rescan with a
// per-lane done mask.  R7 HARDENING: the rescan loop's continuation is now
// WAVE-uniform (__any(ovf)) -- R6's group-local break left __ballot
// executing with partially-active waves (the only theoretically risky
// construct in the R6 run that died without diagnostics).  Finished groups
// idle harmlessly (c>0 guard).
// Geometry: q-tile 64 x panel 128, acc[4][8], 16 panels, LDS 50688 B.
// ---------------------------------------------------------------------------
__global__ __launch_bounds__(256)
void logits_topk(const float* __restrict__ Qh, const float* __restrict__ Kh,
                 float* __restrict__ wbuf)
{
    __shared__ float As[2][32][68];    // both d-chunks of the 64-row Q tile
    __shared__ float Bs[32][132];      // one d-chunk of a 128-row K panel, transposed
    __shared__ u64k  slab[64][32];     // per-row candidate slab (cap 32)

    const int tid = threadIdx.x;
    const int lig = tid & 15;                 // lane in 16-lane group
    const int ty  = tid >> 4;                 // row-group id (0..15)
    const int gsh = ((tid & 63) >> 4) << 4;   // group's bit-shift in wave ballots
    const unsigned ltg = (1u << lig) - 1u;    // lower-lane mask within group (16-bit)
    const int bh = blockIdx.y;
    const int q0 = blockIdx.x * 64;
    const float* Ab = Qh + (size_t)bh * S_LEN * DH;
    const float* Bb = Kh + (size_t)bh * S_LEN * DH;

    // bitonic sort-32 descending across the group, 2 elems/lane at
    // positions (2*lig, 2*lig+1).  Verbatim the R3/R4/R5 HW-verified network.
    auto sort32 = [&](u64k &a0, u64k &a1) {
#pragma unroll
        for (int s = 2; s <= 32; s <<= 1) {
#pragma unroll
            for (int d = s >> 1; d >= 1; d >>= 1) {
                int e0 = 2 * lig;
                if (d == 1) {
                    bool descB = ((e0 & s) == 0);
                    u64k mx = a0 > a1 ? a0 : a1;
                    u64k mn = a0 > a1 ? a1 : a0;
                    a0 = descB ? mx : mn;
                    a1 = descB ? mn : mx;
                } else {
                    bool descB = ((e0 & s) == 0);
                    bool amS   = ((e0 & d) == 0);
                    bool wantMax = (descB == amS);
                    u64k p0 = __shfl_xor(a0, d >> 1, 16);
                    u64k p1 = __shfl_xor(a1, d >> 1, 16);
                    a0 = wantMax ? (a0 > p0 ? a0 : p0) : (a0 > p0 ? p0 : a0);
                    a1 = wantMax ? (a1 > p1 ? a1 : p1) : (a1 > p1 ? p1 : a1);
                }
            }
        }
    };
    // clean a bitonic 32-sequence to descending (stages d=16..1)
    auto clean32 = [&](u64k &a0, u64k &a1) {
#pragma unroll
        for (int d = 16; d >= 2; d >>= 1) {
            bool amS = (((2 * lig) & d) == 0);
            u64k p0 = __shfl_xor(a0, d >> 1, 16);
            u64k p1 = __shfl_xor(a1, d >> 1, 16);
            a0 = amS ? (a0 > p0 ? a0 : p0) : (a0 > p0 ? p0 : a0);
            a1 = amS ? (a1 > p1 ? a1 : p1) : (a1 > p1 ? p1 : a1);
        }
        u64k mx = a0 > a1 ? a0 : a1;
        u64k mn = a0 > a1 ? a1 : a0;
        a0 = mx; a1 = mn;
    };

    float acc[4][8];
#pragma unroll
    for (int i = 0; i < 4; ++i)
#pragma unroll
        for (int j = 0; j < 8; ++j) acc[i][j] = 0.f;

    u64k key0[4], key1[4], botk[4];
    int  cnti[4];
#pragma unroll
    for (int i = 0; i < 4; ++i) { key0[i] = 0; key1[i] = 0; botk[i] = 0; cnti[i] = 0; }

    // stage the Q tile once: As[ch][kk][r] = Q[q0+r][ch*32+kk] * 0.125
    // (identical values to the passing kernel's staging)
#pragma unroll
    for (int u = 0; u < 4; ++u) {
        int id = tid + u * 256;
        int r = id >> 4, c4 = (id & 15) * 4;
        int ch = c4 >> 5, cl = c4 & 31;
        f32x4 x = *(const f32x4*)(Ab + (size_t)(q0 + r) * DH + c4);
        As[ch][cl + 0][r] = x.x * 0.125f;
        As[ch][cl + 1][r] = x.y * 0.125f;
        As[ch][cl + 2][r] = x.z * 0.125f;
        As[ch][cl + 3][r] = x.w * 0.125f;
    }

    // register prefetch of K panel 0, chunk 0 (128 rows x 32 k)
    f32x4 kb[4];
#pragma unroll
    for (int u = 0; u < 4; ++u) {
        int id = tid + u * 256;
        int r = id >> 3, c4 = (id & 7) * 4;
        kb[u] = *(const f32x4*)(Bb + (size_t)r * DH + c4);
    }

#pragma unroll 1
    for (int kp = 0; kp < 16; ++kp) {
        // ---- GEMM for this 64x128 panel ---------------------------------
#pragma unroll
        for (int ch = 0; ch < 2; ++ch) {
            __syncthreads();      // previous phase's Bs readers done
#pragma unroll
            for (int u = 0; u < 4; ++u) {
                int id = tid + u * 256;
                int r = id >> 3, c4 = (id & 7) * 4;
                Bs[c4 + 0][r] = kb[u].x; Bs[c4 + 1][r] = kb[u].y;
                Bs[c4 + 2][r] = kb[u].z; Bs[c4 + 3][r] = kb[u].w;
            }
            __syncthreads();      // Bs (and, first time, As) visible
            {
                int nkp = ch ? kp + 1 : kp;
                int nch = ch ^ 1;
                if (nkp < 16) {
#pragma unroll
                    for (int u = 0; u < 4; ++u) {
                        int id = tid + u * 256;
                        int r = id >> 3, c4 = (id & 7) * 4;
                        kb[u] = *(const f32x4*)(Bb + (size_t)(nkp * 128 + r) * DH + nch * 32 + c4);
                    }
                }
            }
#pragma unroll 8
            for (int kk = 0; kk < 32; ++kk) {
                float a[4], b[8];
                *(f32x4*)&a[0] = *(const f32x4*)&As[ch][kk][ty * 4];
                *(f32x4*)&b[0] = *(const f32x4*)&Bs[kk][lig * 4];
                *(f32x4*)&b[4] = *(const f32x4*)&Bs[kk][64 + lig * 4];
#pragma unroll
                for (int i = 0; i < 4; ++i)
#pragma unroll
                    for (int j = 0; j < 8; ++j)
                        acc[i][j] = fmaf(a[i], b[j], acc[i][j]);
            }
        }

        // ---- exact online top-32: batched scan + sort/merge -------------
        // col of acc[i][j] = kp*128 + (j>>2)*64 + lig*4 + (j&3)
#pragma unroll
        for (int i = 0; i < 4; ++i) {
            unsigned done = 0;
            if (kp == 0) {
                // seed: lane-local top-2 by key, then bitonic sort-32
                u64k t0 = 0, t1 = 0; int j0 = 0, j1 = 0;
#pragma unroll
                for (int j = 0; j < 8; ++j) {
                    u64k kj = make_key(acc[i][j], ((j >> 2) << 6) + (lig << 2) + (j & 3));
                    if (kj > t0)      { t1 = t0; j1 = j0; t0 = kj; j0 = j; }
                    else if (kj > t1) { t1 = kj; j1 = j; }
                }
                key0[i] = t0; key1[i] = t1;
                sort32(key0[i], key1[i]);
                botk[i] = __shfl(key1[i], 15, 16);
                cnti[i] = 0;
                done = (1u << j0) | (1u << j1);
            }
            u64k bk = botk[i];
            int c = cnti[i];
#pragma unroll 1
            for (int att = 0; att < 10; ++att) {
                bool ovf = false;
#pragma unroll
                for (int j = 0; j < 8; ++j) {
                    u64k kj = make_key(acc[i][j],
                                       kp * 128 + ((j >> 2) << 6) + (lig << 2) + (j & 3));
                    bool p = (((done >> j) & 1u) == 0u) && (kj > bk);
                    unsigned long long wbm = __ballot(p);
                    unsigned mk = (unsigned)((wbm >> gsh) & 0xFFFFull);
                    if (mk) {
                        int pos = c + __popc(mk & ltg);
                        int tot = c + __popc(mk);
                        if (p && pos < 32) { slab[ty * 4 + i][pos] = kj; done |= 1u << j; }
                        if (tot > 32) { ovf = true; c = 32; } else { c = tot; }
                    }
                }
                if (c > 0 && (ovf || c >= 24 || kp == 15)) {
                    lds_fence();
                    u64k c0 = (2 * lig     < c) ? slab[ty * 4 + i][2 * lig]     : 0ull;
                    u64k c1 = (2 * lig + 1 < c) ? slab[ty * 4 + i][2 * lig + 1] : 0ull;
                    sort32(c0, c1);
                    // top-32 of union(top32, cand32): z[e]=max(a[e],b[31-e]),
                    // then clean the bitonic result to descending.
                    u64k m0 = __shfl_xor(c1, 15, 16);
                    u64k m1 = __shfl_xor(c0, 15, 16);
                    key0[i] = key0[i] > m0 ? key0[i] : m0;
                    key1[i] = key1[i] > m1 ? key1[i] : m1;
                    clean32(key0[i], key1[i]);
                    bk = __shfl(key1[i], 15, 16);
                    c = 0;
                }
                if (!__any(ovf)) break;   // WAVE-uniform continuation (R7)
            }
            botk[i] = bk;
            cnti[i] = c;
        }

        // reset accumulators for the next panel (keys hold the result)
#pragma unroll
        for (int i = 0; i < 4; ++i)
#pragma unroll
            for (int j = 0; j < 8; ++j) acc[i][j] = 0.f;
    }

    // ---- dump winners: 32 sorted keys into the row's own w row ----------
#pragma unroll
    for (int i = 0; i < 4; ++i) {
        int r = q0 + ty * 4 + i;
        float* wr = wbuf + ((size_t)bh * S_LEN + r) * S_LEN;
        *(u64k*)(wr + (lig << 2))     = key0[i];   // slot 2*lig
        *(u64k*)(wr + (lig << 2) + 2) = key1[i];   // slot 2*lig+1
    }
}

// ---------------------------------------------------------------------------
// Weight transpose + fp16 hi/lo split for Wv (z=0) and Wo (z=1) only.
// ---------------------------------------------------------------------------
__global__ __launch_bounds__(256)
void wsplit2(const float* __restrict__ W0, const float* __restrict__ W1,
             f16* __restrict__ planes)
{
    __shared__ float tile[32][33];
    const float* W = blockIdx.z ? W1 : W0;
    f16* Th = planes + (size_t)blockIdx.z * 524288;
    f16* Tl = Th + 262144;
    const int bx = blockIdx.x * 32;
    const int by = blockIdx.y * 32;
    const int lx = threadIdx.x & 31, ly = threadIdx.x >> 5;
#pragma unroll
    for (int r = ly; r < 32; r += 8)
        tile[r][lx] = W[(size_t)(by + r) * 512 + bx + lx];
    __syncthreads();
#pragma unroll
    for (int r = ly; r < 32; r += 8) {
        float x = tile[lx][r];              // = W[by+lx][bx+r]
        f16 h = (f16)x;
        f16 l = (f16)((x - (float)h) * LO_SCALE);
        Th[(size_t)(bx + r) * 512 + by + lx] = h;
        Tl[(size_t)(bx + r) * 512 + by + lx] = l;
    }
}

// ---------------------------------------------------------------------------
// Split-fp16 MFMA GEMM, A fp32 (in-kernel split): V projection only
// (selection-irrelevant).  mode 1 = fp32 head-split write.
// ---------------------------------------------------------------------------
__global__ __launch_bounds__(256)
void gemm_x32(const float* __restrict__ X,
              const f16* __restrict__ Bh_, const f16* __restrict__ Bl_,
              const float* __restrict__ bias, float* __restrict__ outF, int mode)
{
    __shared__ f16 sm[16384];
    f16* As_h = sm;       f16* As_l = sm + 4096;
    f16* Bs_h = sm + 8192; f16* Bs_l = sm + 12288;
    const int tid  = threadIdx.x;
    const int lane = tid & 63, wv = tid >> 6;
    const int wm = wv & 1, wn = wv >> 1;
    const int quad = lane >> 4, l15 = lane & 15;
    const int m0 = blockIdx.y * 128, n0 = blockIdx.x * 128;

    floatx4 acc_h[4][4], acc_c[4][4];
    const floatx4 z4 = {0.f, 0.f, 0.f, 0.f};
#pragma unroll
    for (int i = 0; i < 4; ++i)
#pragma unroll
        for (int j = 0; j < 4; ++j) { acc_h[i][j] = z4; acc_c[i][j] = z4; }

    for (int k0 = 0; k0 < 512; k0 += 32) {
        __syncthreads();
#pragma unroll
        for (int c = 0; c < 4; ++c) {
            int r   = c * 32 + (tid >> 3);
            int col = (tid & 7) * 4;
            f32x4 x = *(const f32x4*)(X + (size_t)(m0 + r) * 512 + k0 + col);
            f16 h0 = (f16)x.x, h1 = (f16)x.y, h2 = (f16)x.z, h3 = (f16)x.w;
            half4 hv = {h0, h1, h2, h3};
            half4 lv = {(f16)((x.x - (float)h0) * LO_SCALE),
                        (f16)((x.y - (float)h1) * LO_SCALE),
                        (f16)((x.z - (float)h2) * LO_SCALE),
                        (f16)((x.w - (float)h3) * LO_SCALE)};
            *(half4*)&As_h[r * 32 + col] = hv;
            *(half4*)&As_l[r * 32 + col] = lv;
        }
#pragma unroll
        for (int c = 0; c < 2; ++c) {
            int r    = c * 64 + (wv << 4) + (lane >> 2);
            int ch   = (lane & 3) * 8;
            int lidx = (c * 64 + (wv << 4)) * 32 + lane * 8;
            gl_lds16(Bh_ + (size_t)(n0 + r) * 512 + k0 + ch, &Bs_h[lidx]);
            gl_lds16(Bl_ + (size_t)(n0 + r) * 512 + k0 + ch, &Bs_l[lidx]);
        }
        asm volatile("s_waitcnt vmcnt(0)" ::: "memory");
        __syncthreads();

        half8 bh8[4], bl8[4];
#pragma unroll
        for (int j = 0; j < 4; ++j) {
            int n = wn * 64 + j * 16 + l15;
            bh8[j] = *(const half8*)&Bs_h[n * 32 + quad * 8];
            bl8[j] = *(const half8*)&Bs_l[n * 32 + quad * 8];
        }
#pragma unroll
        for (int i = 0; i < 4; ++i) {
            int m = wm * 64 + i * 16 + l15;
            half8 ah = *(const half8*)&As_h[m * 32 + quad * 8];
            half8 al = *(const half8*)&As_l[m * 32 + quad * 8];
#pragma unroll
            for (int j = 0; j < 4; ++j) {
                acc_h[i][j] = __builtin_amdgcn_mfma_f32_16x16x32_f16(ah, bh8[j], acc_h[i][j], 0, 0, 0);
                acc_c[i][j] = __builtin_amdgcn_mfma_f32_16x16x32_f16(ah, bl8[j], acc_c[i][j], 0, 0, 0);
                acc_c[i][j] = __builtin_amdgcn_mfma_f32_16x16x32_f16(al, bh8[j], acc_c[i][j], 0, 0, 0);
            }
        }
    }

#pragma unroll
    for (int j = 0; j < 4; ++j) {
        int col = n0 + wn * 64 + j * 16 + l15;
        float bv = bias[col];
#pragma unroll
        for (int i = 0; i < 4; ++i) {
            int rbase = m0 + wm * 64 + i * 16 + quad * 4;
#pragma unroll
            for (int rg = 0; rg < 4; ++rg) {
                float r = acc_h[i][j][rg] + acc_c[i][j][rg] * INV_LO + bv;
                int row = rbase + rg;
                if (mode == 2) {
                    outF[(size_t)row * 512 + col] = r;
                } else {
                    int b_ = row >> 11, s = row & 2047, h = col >> 6, d = col & 63;
                    outF[(((size_t)(b_ * NH + h)) * S_LEN + s) * DH + d] = r;
                }
            }
        }
    }
}

// ---------------------------------------------------------------------------
// Split-fp16 MFMA GEMM, both operands pre-split planes [row][k].
// mode 2: out-proj (K=512, C = A@B^T + bias, fp32 [8192][512]).
// ---------------------------------------------------------------------------
__global__ __launch_bounds__(256)
void gemm_x16(const f16* __restrict__ Ah_, const f16* __restrict__ Al_,
              const f16* __restrict__ Bh_, const f16* __restrict__ Bl_,
              const float* __restrict__ bias, float* __restrict__ outF,
              int Ksz, int ldc, int mode)
{
    __shared__ f16 sm[16384];
    f16* As_h = sm;        f16* As_l = sm + 4096;
    f16* Bs_h = sm + 8192; f16* Bs_l = sm + 12288;
    const int tid  = threadIdx.x;
    const int lane = tid & 63, wv = tid >> 6;
    const int wm = wv & 1, wn = wv >> 1;
    const int quad = lane >> 4, l15 = lane & 15;
    const int m0 = blockIdx.y * 128, n0 = blockIdx.x * 128;

    floatx4 acc_h[4][4], acc_c[4][4];
    const floatx4 z4 = {0.f, 0.f, 0.f, 0.f};
#pragma unroll
    for (int i = 0; i < 4; ++i)
#pragma unroll
        for (int j = 0; j < 4; ++j) { acc_h[i][j] = z4; acc_c[i][j] = z4; }

    for (int k0 = 0; k0 < Ksz; k0 += 32) {
        __syncthreads();
#pragma unroll
        for (int c = 0; c < 2; ++c) {
            int r    = c * 64 + (wv << 4) + (lane >> 2);
            int ch   = (lane & 3) * 8;
            int lidx = (c * 64 + (wv << 4)) * 32 + lane * 8;
            gl_lds16(Ah_ + (size_t)(m0 + r) * Ksz + k0 + ch, &As_h[lidx]);
            gl_lds16(Al_ + (size_t)(m0 + r) * Ksz + k0 + ch, &As_l[lidx]);
            gl_lds16(Bh_ + (size_t)(n0 + r) * Ksz + k0 + ch, &Bs_h[lidx]);
            gl_lds16(Bl_ + (size_t)(n0 + r) * Ksz + k0 + ch, &Bs_l[lidx]);
        }
        asm volatile("s_waitcnt vmcnt(0)" ::: "memory");
        __syncthreads();

        half8 bh8[4], bl8[4];
#pragma unroll
        for (int j = 0; j < 4; ++j) {
            int n = wn * 64 + j * 16 + l15;
            bh8[j] = *(const half8*)&Bs_h[n * 32 + quad * 8];
            bl8[j] = *(const half8*)&Bs_l[n * 32 + quad * 8];
        }
#pragma unroll
        for (int i = 0; i < 4; ++i) {
            int m = wm * 64 + i * 16 + l15;
            half8 ah = *(const half8*)&As_h[m * 32 + quad * 8];
            half8 al = *(const half8*)&As_l[m * 32 + quad * 8];
#pragma unroll
            for (int j = 0; j < 4; ++j) {
                acc_h[i][j] = __builtin_amdgcn_mfma_f32_16x16x32_f16(ah, bh8[j], acc_h[i][j], 0, 0, 0);
                acc_c[i][j] = __builtin_amdgcn_mfma_f32_16x16x32_f16(ah, bl8[j], acc_c[i][j], 0, 0, 0);
                acc_c[i][j] = __builtin_amdgcn_mfma_f32_16x16x32_f16(al, bh8[j], acc_c[i][j], 0, 0, 0);
            }
        }
    }

#pragma unroll
    for (int j = 0; j < 4; ++j) {
        int col = n0 + wn * 64 + j * 16 + l15;
        float bv = (mode == 2) ? bias[col] : 0.f;
#pragma unroll
        for (int i = 0; i < 4; ++i) {
            int rbase = m0 + wm * 64 + i * 16 + quad * 4;
#pragma unroll
            for (int rg = 0; rg < 4; ++rg) {
                float r = acc_h[i][j][rg] + acc_c[i][j][rg] * INV_LO;
                int row = rbase + rg;
                outF[(size_t)row * ldc + col] = r + bv;
            }
        }
    }
}

// ---------------------------------------------------------------------------
// Scatter + sparse attention.  One wave per query row.  Reads the row's 32
// pre-ranked winner keys (first 256 B of its own w row, written by
// logits_topk), computes e=exp(v-m) exactly as before (m = rank-0 = row
// max), renormalizes, then zero+scatter+NT-stream of the full w row and the
// 32-term weighted V sum.  No logits re-read, no threshold search.
// ---------------------------------------------------------------------------
__global__ __launch_bounds__(256)
void topk_scatter(float* __restrict__ wbuf, const float* __restrict__ Vh,
                  f16* __restrict__ attH, f16* __restrict__ attL)
{
    __shared__ float wrow[4][2048];
    __shared__ float win_w[4][TOPK];
    __shared__ int   win_i[4][TOPK];

    const int tid  = threadIdx.x;
    const int wv   = tid >> 6;
    const int lane = tid & 63;
    const int row  = blockIdx.x * 4 + wv;       // (b*8+h)*2048 + s
    float* wr = wbuf + (size_t)row * 2048;

    u64k key = 0;
    if (lane < TOPK) key = ((const u64k*)wr)[lane];
    unsigned sv = (unsigned)(key >> 16);
    unsigned fu = (sv & 0x80000000u) ? (sv ^ 0x80000000u) : ~sv;
    float v = __uint_as_float(fu);
    int idx = (int)(0xFFFFu - (unsigned)(key & 0xFFFFull)) & 2047;

    float m = __shfl(v, 0, 64);                 // rank-0 value = row max
    float e = (lane < TOPK) ? __expf(v - m) : 0.f;

    float mysum = e;
#pragma unroll
    for (int off = 32; off > 0; off >>= 1) mysum += __shfl_xor(mysum, off, 64);
    const float rw = 1.f / mysum;

    if (lane < TOPK) { win_w[wv][lane] = e; win_i[wv][lane] = idx; }

    const f32x4 z = {0.f, 0.f, 0.f, 0.f};
#pragma unroll
    for (int t = 0; t < 8; ++t) ((f32x4*)wrow[wv])[t * 64 + lane] = z;
    lds_fence();
    if (lane < TOPK) wrow[wv][win_i[wv][lane]] = win_w[wv][lane] * rw;
    lds_fence();

    // stream the sparse w row out (overwrites the winner-key scratch too)
#pragma unroll
    for (int t = 0; t < 8; ++t)
        __builtin_nontemporal_store(((f32x4*)wrow[wv])[t * 64 + lane],
                                    (f32x4*)(wr + (size_t)(t * 64 + lane) * 4));

    // sparse attention: 32 weighted V rows; lane = head-dim index
    const int bh = row >> 11;
    const float* Vb = Vh + (size_t)bh * S_LEN * DH;
    float acc = 0.f;
#pragma unroll
    for (int j = 0; j < TOPK; ++j) {
        float wj = win_w[wv][j] * rw;
        int   kj = win_i[wv][j];
        acc = fmaf(wj, Vb[(size_t)kj * DH + lane], acc);
    }
    const int b_ = row >> 14;
    const int h  = (row >> 11) & 7;
    const int s  = row & 2047;
    size_t oidx = (((size_t)b_ * S_LEN) + s) * 512 + h * DH + lane;
    f16 hh = (f16)acc;
    attH[oidx] = hh;
    attL[oidx] = (f16)((acc - (float)hh) * LO_SCALE);
}

// ---------------------------------------------------------------------------
extern "C" void kernel_launch(void* const* d_in, const int* in_sizes, int n_in,
                              void* d_out, int out_size, void* d_ws, size_t ws_size,
                              hipStream_t stream) {
    const float* v  = (const float*)d_in[0];
    const float* k  = (const float*)d_in[1];
    const float* q  = (const float*)d_in[2];
    const float* Wq = (const float*)d_in[3];
    const float* bq = (const float*)d_in[4];
    const float* Wk = (const float*)d_in[5];
    const float* bk = (const float*)d_in[6];
    const float* Wv = (const float*)d_in[7];
    const float* bv = (const float*)d_in[8];
    const float* Wo = (const float*)d_in[9];
    const float* bo = (const float*)d_in[10];

    float* out  = (float*)d_out;                    // [4,2048,512]
    float* wout = out + (size_t)4 * S_LEN * 512;    // [4,8,2048,2048] w output

    char* ws = (char*)d_ws;
    float* Vh   = (float*)ws;                       // fp32 [B,H,S,dh], 16 MB
    float* Qh32 = (float*)(ws + 16777216);          // fp32 [B,H,S,dh], 16 MB
    float* Kh32 = (float*)(ws + 33554432);          // fp32 [B,H,S,dh], 16 MB
    f16* WT  = (f16*)(ws + 50331648);               // 4 planes of 512x512, 2 MB
    f16 *WvH = WT,           *WvL = WT + 262144;
    f16 *WoH = WT + 524288,  *WoL = WT + 786432;
    // att planes alias Qh32 (dead after logits_topk): 8 MB + 8 MB
    f16* attH = (f16*)(ws + 16777216);
    f16* attL = (f16*)(ws + 25165824);

    wsplit2<<<dim3(16, 16, 2), 256, 0, stream>>>(Wv, Wo, WT);

    qkproj<<<dim3(4, 64, 2), 256, 0, stream>>>(q, k, Wq, Wk, bq, bk, Qh32, Kh32);
    gemm_x32<<<dim3(4, 64), 256, 0, stream>>>(v, WvH, WvL, bv, Vh, 1);

    logits_topk<<<dim3(32, 32), 256, 0, stream>>>(Qh32, Kh32, wout);

    topk_scatter<<<16384, 256, 0, stream>>>(wout, Vh, attH, attL);

    gemm_x16<<<dim3(4, 64, 1), 256, 0, stream>>>(attH, attL, WoH, WoL, bo, out, 512, 512, 2);
}

// Round 8
// 1194.500 us; speedup vs baseline: 1.3451x; 1.0631x over previous
//
#include <hip/hip_runtime.h>
#include <hip/hip_bf16.h>
#include <stdint.h>

#define S_LEN 2048
#define DMODEL 512
#define NH 8
#define DH 64
#define TOPK 32
#define LO_SCALE 4096.0f
#define INV_LO (1.0f/4096.0f)

typedef _Float16 f16;
typedef f16 half8 __attribute__((ext_vector_type(8)));
typedef f16 half4 __attribute__((ext_vector_type(4)));
typedef float floatx4 __attribute__((ext_vector_type(4)));
typedef float f32x4 __attribute__((ext_vector_type(4)));
typedef unsigned long long u64k;

#define AS1 __attribute__((address_space(1)))
#define AS3 __attribute__((address_space(3)))

__device__ __forceinline__ void gl_lds16(const void* g, void* l) {
    __builtin_amdgcn_global_load_lds((const AS1 void*)g, (AS3 void*)l, 16, 0, 0);
}
__device__ __forceinline__ void lds_fence() {
    asm volatile("s_waitcnt lgkmcnt(0)" ::: "memory");
}

// key = sortable(value) in bits [47:16], (0xFFFF - idx) in [15:0]
// -> u64 compare == (value desc, idx asc), identical tie-break to the
// previously passing packed-key scheme.
__device__ __forceinline__ u64k make_key(float f, int idx) {
    unsigned u = __float_as_uint(f);
    unsigned sv = u ^ ((unsigned)(((int)u) >> 31) | 0x80000000u);
    return ((u64k)sv << 16) | (u64k)(0xFFFFu - (unsigned)idx);
}

// ---------------------------------------------------------------------------
// Merged Q+K projection, fp32 vector GEMM.  SELECTION-CRITICAL: per-output
// fma order k=0..511 ascending, identical staging values -> BIT-IDENTICAL.
// 128x128 tile (grid 512 = 2 blocks/CU) with conflict-free grouped-4
// fragment mapping.
// ---------------------------------------------------------------------------
__global__ __launch_bounds__(256)
void qkproj(const float* __restrict__ Xq, const float* __restrict__ Xk,
            const float* __restrict__ Wq_, const float* __restrict__ Wk_,
            const float* __restrict__ bq_, const float* __restrict__ bk_,
            float* __restrict__ outQ, float* __restrict__ outK)
{
    __shared__ float As[32][132];   // [k][m]
    __shared__ float Bs[32][132];   // [k][n]
    const float* X    = blockIdx.z ? Xk  : Xq;
    const float* W    = blockIdx.z ? Wk_ : Wq_;
    const float* bias = blockIdx.z ? bk_ : bq_;
    float* out        = blockIdx.z ? outK : outQ;
    const int tid = threadIdx.x;
    const int tx = tid & 15;        // n: cols tx*4 + h*64, h=0..1
    const int ty = tid >> 4;        // m: rows ty*4 + g*64, g=0..1
    const int m0 = blockIdx.y * 128;
    const int n0 = blockIdx.x * 128;

    float acc[8][8];
#pragma unroll
    for (int i = 0; i < 8; ++i)
#pragma unroll
        for (int j = 0; j < 8; ++j) acc[i][j] = 0.f;

    f32x4 pa[4], pb[4];
#pragma unroll
    for (int u = 0; u < 4; ++u) {
        int id = tid + u * 256;
        pa[u] = *(const f32x4*)(X + (size_t)(m0 + (id >> 3)) * 512 + (id & 7) * 4);
        pb[u] = *(const f32x4*)(W + (size_t)(id >> 5) * 512 + n0 + (id & 31) * 4);
    }

    for (int k0 = 0; k0 < 512; k0 += 32) {
#pragma unroll
        for (int u = 0; u < 4; ++u) {
            int id = tid + u * 256;
            int r = id >> 3, c4 = (id & 7) * 4;
            As[c4 + 0][r] = pa[u].x; As[c4 + 1][r] = pa[u].y;
            As[c4 + 2][r] = pa[u].z; As[c4 + 3][r] = pa[u].w;
            int rb = id >> 5, cb = (id & 31) * 4;
            *(f32x4*)&Bs[rb][cb] = pb[u];
        }
        __syncthreads();
        if (k0 < 480) {
            int kn = k0 + 32;
#pragma unroll
            for (int u = 0; u < 4; ++u) {
                int id = tid + u * 256;
                pa[u] = *(const f32x4*)(X + (size_t)(m0 + (id >> 3)) * 512 + kn + (id & 7) * 4);
                pb[u] = *(const f32x4*)(W + (size_t)(kn + (id >> 5)) * 512 + n0 + (id & 31) * 4);
            }
        }
#pragma unroll 8
        for (int kk = 0; kk < 32; ++kk) {
            float a[8], b[8];
            *(f32x4*)&a[0] = *(const f32x4*)&As[kk][ty * 4];
            *(f32x4*)&a[4] = *(const f32x4*)&As[kk][64 + ty * 4];
            *(f32x4*)&b[0] = *(const f32x4*)&Bs[kk][tx * 4];
            *(f32x4*)&b[4] = *(const f32x4*)&Bs[kk][64 + tx * 4];
#pragma unroll
            for (int i = 0; i < 8; ++i)
#pragma unroll
                for (int j = 0; j < 8; ++j)
                    acc[i][j] = fmaf(a[i], b[j], acc[i][j]);
        }
        __syncthreads();
    }

    float bb[8];
    *(f32x4*)&bb[0] = *(const f32x4*)(bias + n0 + tx * 4);
    *(f32x4*)&bb[4] = *(const f32x4*)(bias + n0 + 64 + tx * 4);

#pragma unroll
    for (int i = 0; i < 8; ++i) {
        int r = m0 + ((i >> 2) << 6) + ty * 4 + (i & 3);
        int b_ = r >> 11, s = r & 2047;
#pragma unroll
        for (int h = 0; h < 2; ++h) {
            int c = n0 + h * 64 + tx * 4;
            f32x4 w = {acc[i][h * 4 + 0] + bb[h * 4 + 0],
                       acc[i][h * 4 + 1] + bb[h * 4 + 1],
                       acc[i][h * 4 + 2] + bb[h * 4 + 2],
                       acc[i][h * 4 + 3] + bb[h * 4 + 3]};
            int hd = c >> 6, d = c & 63;
            float* p = out + (((size_t)(b_ * NH + hd) * S_LEN) + s) * DH + d;
            *(f32x4*)p = w;
        }
    }
}

// ---------------------------------------------------------------------------
// FUSED fp32 logits + exact top-32.  SELECTION-CRITICAL invariants:
//  * logits bits: per output, fma chain (d-chunk 0 asc kk, chunk 1 asc kk)
//    with A staged as Q*0.125 -- IDENTICAL ops/order to the passing kernel
//    (panel width never enters a chain; acc zeroed per panel).
//  * winner set: exact top-32 by key (value desc, idx asc) via batched
//    ballot-append + bitonic sort-32/merge (R7's HW-passed network).
// R8 STRUCTURE: R7 was LDS-read-bound (3 ds_read_b128 / 32 fma, 2 blocks/CU).
//  (1) 16-col panels (acc[4][16], panel 256, 8 panels = R5's HW-passed GEMM
//      geometry): 5 b128 / 64 fma -> 17% less LDS traffic, half the scan
//      phases.
//  (2) slab ALIASES Bs (dead during top-k): LDS 50688 stays but slab is
//      free -> 3 blocks/CU.  Requires __syncthreads after the ch-loop and
//      merge-at-every-panel-end (slab never survives a panel) -- still
//      exact (merge-of-union is order-independent; zero-keys are no-ops).
//  (3) ALL merge control flow wave-uniform (__any-driven; final merge
//      unconditional) -- no group-divergent branches around cross-lane ops.
// ---------------------------------------------------------------------------
__global__ __launch_bounds__(256)
void logits_topk(const float* __restrict__ Qh, const float* __restrict__ Kh,
                 float* __restrict__ wbuf)
{
    __shared__ float As[2][32][68];                 // both d-chunks of 64-row Q tile
    __shared__ __align__(16) char smemB[33280];     // Bs[32][260] floats; slab aliases
    float* Bs = (float*)smemB;                      // Bs[kk*260 + col]
    u64k (*slab)[32] = (u64k(*)[32])smemB;          // [64][32] u64 (16384 B <= 33280)

    const int tid = threadIdx.x;
    const int lig = tid & 15;                 // lane in 16-lane group
    const int ty  = tid >> 4;                 // row-group id (0..15)
    const int gsh = ((tid & 63) >> 4) << 4;   // group's bit-shift in wave ballots
    const unsigned ltg = (1u << lig) - 1u;    // lower-lane mask within group (16-bit)
    const int bh = blockIdx.y;
    const int q0 = blockIdx.x * 64;
    const float* Ab = Qh + (size_t)bh * S_LEN * DH;
    const float* Bb = Kh + (size_t)bh * S_LEN * DH;

    // bitonic sort-32 descending across the group, 2 elems/lane (HW-verified)
    auto sort32 = [&](u64k &a0, u64k &a1) {
#pragma unroll
        for (int s = 2; s <= 32; s <<= 1) {
#pragma unroll
            for (int d = s >> 1; d >= 1; d >>= 1) {
                int e0 = 2 * lig;
                if (d == 1) {
                    bool descB = ((e0 & s) == 0);
                    u64k mx = a0 > a1 ? a0 : a1;
                    u64k mn = a0 > a1 ? a1 : a0;
                    a0 = descB ? mx : mn;
                    a1 = descB ? mn : mx;
                } else {
                    bool descB = ((e0 & s) == 0);
                    bool amS   = ((e0 & d) == 0);
                    bool wantMax = (descB == amS);
                    u64k p0 = __shfl_xor(a0, d >> 1, 16);
                    u64k p1 = __shfl_xor(a1, d >> 1, 16);
                    a0 = wantMax ? (a0 > p0 ? a0 : p0) : (a0 > p0 ? p0 : a0);
                    a1 = wantMax ? (a1 > p1 ? a1 : p1) : (a1 > p1 ? p1 : a1);
                }
            }
        }
    };
    // clean a bitonic 32-sequence to descending (stages d=16..1)
    auto clean32 = [&](u64k &a0, u64k &a1) {
#pragma unroll
        for (int d = 16; d >= 2; d >>= 1) {
            bool amS = (((2 * lig) & d) == 0);
            u64k p0 = __shfl_xor(a0, d >> 1, 16);
            u64k p1 = __shfl_xor(a1, d >> 1, 16);
            a0 = amS ? (a0 > p0 ? a0 : p0) : (a0 > p0 ? p0 : a0);
            a1 = amS ? (a1 > p1 ? a1 : p1) : (a1 > p1 ? p1 : a1);
        }
        u64k mx = a0 > a1 ? a0 : a1;
        u64k mn = a0 > a1 ? a1 : a0;
        a0 = mx; a1 = mn;
    };

    float acc[4][16];
#pragma unroll
    for (int i = 0; i < 4; ++i)
#pragma unroll
        for (int j = 0; j < 16; ++j) acc[i][j] = 0.f;

    u64k key0[4], key1[4], botk[4];
#pragma unroll
    for (int i = 0; i < 4; ++i) { key0[i] = 0; key1[i] = 0; botk[i] = 0; }

    // stage the Q tile once: As[ch][kk][r] = Q[q0+r][ch*32+kk] * 0.125
#pragma unroll
    for (int u = 0; u < 4; ++u) {
        int id = tid + u * 256;
        int r = id >> 4, c4 = (id & 15) * 4;
        int ch = c4 >> 5, cl = c4 & 31;
        f32x4 x = *(const f32x4*)(Ab + (size_t)(q0 + r) * DH + c4);
        As[ch][cl + 0][r] = x.x * 0.125f;
        As[ch][cl + 1][r] = x.y * 0.125f;
        As[ch][cl + 2][r] = x.z * 0.125f;
        As[ch][cl + 3][r] = x.w * 0.125f;
    }

    // register prefetch of K panel 0, chunk 0 (256 rows x 32 k)
    f32x4 kb[8];
#pragma unroll
    for (int u = 0; u < 8; ++u) {
        int id = tid + u * 256;
        int r = id >> 3, c4 = (id & 7) * 4;
        kb[u] = *(const f32x4*)(Bb + (size_t)r * DH + c4);
    }

#pragma unroll 1
    for (int kp = 0; kp < 8; ++kp) {
        // ---- GEMM for this 64x256 panel ---------------------------------
#pragma unroll
        for (int ch = 0; ch < 2; ++ch) {
            __syncthreads();      // prev Bs/slab users done
#pragma unroll
            for (int u = 0; u < 8; ++u) {
                int id = tid + u * 256;
                int r = id >> 3, c4 = (id & 7) * 4;
                Bs[(c4 + 0) * 260 + r] = kb[u].x;
                Bs[(c4 + 1) * 260 + r] = kb[u].y;
                Bs[(c4 + 2) * 260 + r] = kb[u].z;
                Bs[(c4 + 3) * 260 + r] = kb[u].w;
            }
            __syncthreads();      // Bs (and, first time, As) visible
            {
                int nkp = ch ? kp + 1 : kp;
                int nch = ch ^ 1;
                if (nkp < 8) {
#pragma unroll
                    for (int u = 0; u < 8; ++u) {
                        int id = tid + u * 256;
                        int r = id >> 3, c4 = (id & 7) * 4;
                        kb[u] = *(const f32x4*)(Bb + (size_t)(nkp * 256 + r) * DH + nch * 32 + c4);
                    }
                }
            }
#pragma unroll 8
            for (int kk = 0; kk < 32; ++kk) {
                float a[4], b[16];
                *(f32x4*)&a[0] = *(const f32x4*)&As[ch][kk][ty * 4];
#pragma unroll
                for (int h = 0; h < 4; ++h)
                    *(f32x4*)&b[h * 4] = *(const f32x4*)&Bs[kk * 260 + lig * 4 + h * 64];
#pragma unroll
                for (int i = 0; i < 4; ++i)
#pragma unroll
                    for (int j = 0; j < 16; ++j)
                        acc[i][j] = fmaf(a[i], b[j], acc[i][j]);
            }
        }
        __syncthreads();   // ALL waves done reading Bs before slab (alias) writes

        // ---- exact online top-32: batched scan + sort/merge -------------
        // col of acc[i][j] = kp*256 + (j>>2)*64 + lig*4 + (j&3)
#pragma unroll
        for (int i = 0; i < 4; ++i) {
            unsigned done = 0;
            if (kp == 0) {
                // seed: lane-local top-2 by key, then bitonic sort-32
                u64k t0 = 0, t1 = 0; int j0 = 0, j1 = 0;
#pragma unroll
                for (int j = 0; j < 16; ++j) {
                    u64k kj = make_key(acc[i][j], ((j >> 2) << 6) + (lig << 2) + (j & 3));
                    if (kj > t0)      { t1 = t0; j1 = j0; t0 = kj; j0 = j; }
                    else if (kj > t1) { t1 = kj; j1 = j; }
                }
                key0[i] = t0; key1[i] = t1;
                sort32(key0[i], key1[i]);
                botk[i] = __shfl(key1[i], 15, 16);
                done = (1u << j0) | (1u << j1);
            }
            u64k bk = botk[i];
            int c = 0;
            // <=256 candidates; each overflow pass absorbs 32 -> <=9 passes
#pragma unroll 1
            for (int att = 0; att < 12; ++att) {
                bool ovf = false;
#pragma unroll
                for (int j = 0; j < 16; ++j) {
                    u64k kj = make_key(acc[i][j],
                                       kp * 256 + ((j >> 2) << 6) + (lig << 2) + (j & 3));
                    bool p = (((done >> j) & 1u) == 0u) && (kj > bk);
                    unsigned long long wbm = __ballot(p);
                    unsigned mk = (unsigned)((wbm >> gsh) & 0xFFFFull);
                    if (mk) {
                        int pos = c + __popc(mk & ltg);
                        int tot = c + __popc(mk);
                        if (p && pos < 32) { slab[ty * 4 + i][pos] = kj; done |= 1u << j; }
                        if (tot > 32) { ovf = true; c = 32; } else { c = tot; }
                    }
                }
                bool anyovf = __any(ovf);           // wave-uniform
                if (anyovf) {
                    lds_fence();
                    u64k c0 = (2 * lig     < c) ? slab[ty * 4 + i][2 * lig]     : 0ull;
                    u64k c1 = (2 * lig + 1 < c) ? slab[ty * 4 + i][2 * lig + 1] : 0ull;
                    sort32(c0, c1);
                    u64k m0 = __shfl_xor(c1, 15, 16);
                    u64k m1 = __shfl_xor(c0, 15, 16);
                    key0[i] = key0[i] > m0 ? key0[i] : m0;
                    key1[i] = key1[i] > m1 ? key1[i] : m1;
                    clean32(key0[i], key1[i]);
                    bk = __shfl(key1[i], 15, 16);
                    c = 0;
                } else {
                    break;
                }
            }
            // final merge for this panel (slab dies at next barrier);
            // unconditional -> wave-uniform; c==0 groups merge zero-keys (no-op)
            {
                lds_fence();
                u64k c0 = (2 * lig     < c) ? slab[ty * 4 + i][2 * lig]     : 0ull;
                u64k c1 = (2 * lig + 1 < c) ? slab[ty * 4 + i][2 * lig + 1] : 0ull;
                sort32(c0, c1);
                u64k m0 = __shfl_xor(c1, 15, 16);
                u64k m1 = __shfl_xor(c0, 15, 16);
                key0[i] = key0[i] > m0 ? key0[i] : m0;
                key1[i] = key1[i] > m1 ? key1[i] : m1;
                clean32(key0[i], key1[i]);
                bk = __shfl(key1[i], 15, 16);
            }
            botk[i] = bk;
        }

        // reset accumulators for the next panel (keys hold the result)
#pragma unroll
        for (int i = 0; i < 4; ++i)
#pragma unroll
            for (int j = 0; j < 16; ++j) acc[i][j] = 0.f;
    }

    // ---- dump winners: 32 sorted keys into the row's own w row ----------
#pragma unroll
    for (int i = 0; i < 4; ++i) {
        int r = q0 + ty * 4 + i;
        float* wr = wbuf + ((size_t)bh * S_LEN + r) * S_LEN;
        *(u64k*)(wr + (lig << 2))     = key0[i];   // slot 2*lig
        *(u64k*)(wr + (lig << 2) + 2) = key1[i];   // slot 2*lig+1
    }
}

// ---------------------------------------------------------------------------
// Weight transpose + fp16 hi/lo split for Wv (z=0) and Wo (z=1) only.
// ---------------------------------------------------------------------------
__global__ __launch_bounds__(256)
void wsplit2(const float* __restrict__ W0, const float* __restrict__ W1,
             f16* __restrict__ planes)
{
    __shared__ float tile[32][33];
    const float* W = blockIdx.z ? W1 : W0;
    f16* Th = planes + (size_t)blockIdx.z * 524288;
    f16* Tl = Th + 262144;
    const int bx = blockIdx.x * 32;
    const int by = blockIdx.y * 32;
    const int lx = threadIdx.x & 31, ly = threadIdx.x >> 5;
#pragma unroll
    for (int r = ly; r < 32; r += 8)
        tile[r][lx] = W[(size_t)(by + r) * 512 + bx + lx];
    __syncthreads();
#pragma unroll
    for (int r = ly; r < 32; r += 8) {
        float x = tile[lx][r];              // = W[by+lx][bx+r]
        f16 h = (f16)x;
        f16 l = (f16)((x - (float)h) * LO_SCALE);
        Th[(size_t)(bx + r) * 512 + by + lx] = h;
        Tl[(size_t)(bx + r) * 512 + by + lx] = l;
    }
}

// ---------------------------------------------------------------------------
// Split-fp16 MFMA GEMM, A fp32 (in-kernel split): V projection only
// (selection-irrelevant).  mode 1 = fp32 head-split write.
// ---------------------------------------------------------------------------
__global__ __launch_bounds__(256)
void gemm_x32(const float* __restrict__ X,
              const f16* __restrict__ Bh_, const f16* __restrict__ Bl_,
              const float* __restrict__ bias, float* __restrict__ outF, int mode)
{
    __shared__ f16 sm[16384];
    f16* As_h = sm;       f16* As_l = sm + 4096;
    f16* Bs_h = sm + 8192; f16* Bs_l = sm + 12288;
    const int tid  = threadIdx.x;
    const int lane = tid & 63, wv = tid >> 6;
    const int wm = wv & 1, wn = wv >> 1;
    const int quad = lane >> 4, l15 = lane & 15;
    const int m0 = blockIdx.y * 128, n0 = blockIdx.x * 128;

    floatx4 acc_h[4][4], acc_c[4][4];
    const floatx4 z4 = {0.f, 0.f, 0.f, 0.f};
#pragma unroll
    for (int i = 0; i < 4; ++i)
#pragma unroll
        for (int j = 0; j < 4; ++j) { acc_h[i][j] = z4; acc_c[i][j] = z4; }

    for (int k0 = 0; k0 < 512; k0 += 32) {
        __syncthreads();
#pragma unroll
        for (int c = 0; c < 4; ++c) {
            int r   = c * 32 + (tid >> 3);
            int col = (tid & 7) * 4;
            f32x4 x = *(const f32x4*)(X + (size_t)(m0 + r) * 512 + k0 + col);
            f16 h0 = (f16)x.x, h1 = (f16)x.y, h2 = (f16)x.z, h3 = (f16)x.w;
            half4 hv = {h0, h1, h2, h3};
            half4 lv = {(f16)((x.x - (float)h0) * LO_SCALE),
                        (f16)((x.y - (float)h1) * LO_SCALE),
                        (f16)((x.z - (float)h2) * LO_SCALE),
                        (f16)((x.w - (float)h3) * LO_SCALE)};
            *(half4*)&As_h[r * 32 + col] = hv;
            *(half4*)&As_l[r * 32 + col] = lv;
        }
#pragma unroll
        for (int c = 0; c < 2; ++c) {
            int r    = c * 64 + (wv << 4) + (lane >> 2);
            int ch   = (lane & 3) * 8;
            int lidx = (c * 64 + (wv << 4)) * 32 + lane * 8;
            gl_lds16(Bh_ + (size_t)(n0 + r) * 512 + k0 + ch, &Bs_h[lidx]);
            gl_lds16(Bl_ + (size_t)(n0 + r) * 512 + k0 + ch, &Bs_l[lidx]);
        }
        asm volatile("s_waitcnt vmcnt(0)" ::: "memory");
        __syncthreads();

        half8 bh8[4], bl8[4];
#pragma unroll
        for (int j = 0; j < 4; ++j) {
            int n = wn * 64 + j * 16 + l15;
            bh8[j] = *(const half8*)&Bs_h[n * 32 + quad * 8];
            bl8[j] = *(const half8*)&Bs_l[n * 32 + quad * 8];
        }
#pragma unroll
        for (int i = 0; i < 4; ++i) {
            int m = wm * 64 + i * 16 + l15;
            half8 ah = *(const half8*)&As_h[m * 32 + quad * 8];
            half8 al = *(const half8*)&As_l[m * 32 + quad * 8];
#pragma unroll
            for (int j = 0; j < 4; ++j) {
                acc_h[i][j] = __builtin_amdgcn_mfma_f32_16x16x32_f16(ah, bh8[j], acc_h[i][j], 0, 0, 0);
                acc_c[i][j] = __builtin_amdgcn_mfma_f32_16x16x32_f16(ah, bl8[j], acc_c[i][j], 0, 0, 0);
                acc_c[i][j] = __builtin_amdgcn_mfma_f32_16x16x32_f16(al, bh8[j], acc_c[i][j], 0, 0, 0);
            }
        }
    }

#pragma unroll
    for (int j = 0; j < 4; ++j) {
        int col = n0 + wn * 64 + j * 16 + l15;
        float bv = bias[col];
#pragma unroll
        for (int i = 0; i < 4; ++i) {
            int rbase = m0 + wm * 64 + i * 16 + quad * 4;
#pragma unroll
            for (int rg = 0; rg < 4; ++rg) {
                float r = acc_h[i][j][rg] + acc_c[i][j][rg] * INV_LO + bv;
                int row = rbase + rg;
                if (mode == 2) {
                    outF[(size_t)row * 512 + col] = r;
                } else {
                    int b_ = row >> 11, s = row & 2047, h = col >> 6, d = col & 63;
                    outF[(((size_t)(b_ * NH + h)) * S_LEN + s) * DH + d] = r;
                }
            }
        }
    }
}

// ---------------------------------------------------------------------------
// Split-fp16 MFMA GEMM, both operands pre-split planes [row][k].
// mode 2: out-proj (K=512, C = A@B^T + bias, fp32 [8192][512]).
// ---------------------------------------------------------------------------
__global__ __launch_bounds__(256)
void gemm_x16(const f16* __restrict__ Ah_, const f16* __restrict__ Al_,
              const f16* __restrict__ Bh_, const f16* __restrict__ Bl_,
              const float* __restrict__ bias, float* __restrict__ outF,
              int Ksz, int ldc, int mode)
{
    __shared__ f16 sm[16384];
    f16* As_h = sm;        f16* As_l = sm + 4096;
    f16* Bs_h = sm + 8192; f16* Bs_l = sm + 12288;
    const int tid  = threadIdx.x;
    const int lane = tid & 63, wv = tid >> 6;
    const int wm = wv & 1, wn = wv >> 1;
    const int quad = lane >> 4, l15 = lane & 15;
    const int m0 = blockIdx.y * 128, n0 = blockIdx.x * 128;

    floatx4 acc_h[4][4], acc_c[4][4];
    const floatx4 z4 = {0.f, 0.f, 0.f, 0.f};
#pragma unroll
    for (int i = 0; i < 4; ++i)
#pragma unroll
        for (int j = 0; j < 4; ++j) { acc_h[i][j] = z4; acc_c[i][j] = z4; }

    for (int k0 = 0; k0 < Ksz; k0 += 32) {
        __syncthreads();
#pragma unroll
        for (int c = 0; c < 2; ++c) {
            int r    = c * 64 + (wv << 4) + (lane >> 2);
            int ch   = (lane & 3) * 8;
            int lidx = (c * 64 + (wv << 4)) * 32 + lane * 8;
            gl_lds16(Ah_ + (size_t)(m0 + r) * Ksz + k0 + ch, &As_h[lidx]);
            gl_lds16(Al_ + (size_t)(m0 + r) * Ksz + k0 + ch, &As_l[lidx]);
            gl_lds16(Bh_ + (size_t)(n0 + r) * Ksz + k0 + ch, &Bs_h[lidx]);
            gl_lds16(Bl_ + (size_t)(n0 + r) * Ksz + k0 + ch, &Bs_l[lidx]);
        }
        asm volatile("s_waitcnt vmcnt(0)" ::: "memory");
        __syncthreads();

        half8 bh8[4], bl8[4];
#pragma unroll
        for (int j = 0; j < 4; ++j) {
            int n = wn * 64 + j * 16 + l15;
            bh8[j] = *(const half8*)&Bs_h[n * 32 + quad * 8];
            bl8[j] = *(const half8*)&Bs_l[n * 32 + quad * 8];
        }
#pragma unroll
        for (int i = 0; i < 4; ++i) {
            int m = wm * 64 + i * 16 + l15;
            half8 ah = *(const half8*)&As_h[m * 32 + quad * 8];
            half8 al = *(const half8*)&As_l[m * 32 + quad * 8];
#pragma unroll
            for (int j = 0; j < 4; ++j) {
                acc_h[i][j] = __builtin_amdgcn_mfma_f32_16x16x32_f16(ah, bh8[j], acc_h[i][j], 0, 0, 0);
                acc_c[i][j] = __builtin_amdgcn_mfma_f32_16x16x32_f16(ah, bl8[j], acc_c[i][j], 0, 0, 0);
                acc_c[i][j] = __builtin_amdgcn_mfma_f32_16x16x32_f16(al, bh8[j], acc_c[i][j], 0, 0, 0);
            }
        }
    }

#pragma unroll
    for (int j = 0; j < 4; ++j) {
        int col = n0 + wn * 64 + j * 16 + l15;
        float bv = (mode == 2) ? bias[col] : 0.f;
#pragma unroll
        for (int i = 0; i < 4; ++i) {
            int rbase = m0 + wm * 64 + i * 16 + quad * 4;
#pragma unroll
            for (int rg = 0; rg < 4; ++rg) {
                float r = acc_h[i][j][rg] + acc_c[i][j][rg] * INV_LO;
                int row = rbase + rg;
                outF[(size_t)row * ldc + col] = r + bv;
            }
        }
    }
}

// ---------------------------------------------------------------------------
// Scatter + sparse attention.  One wave per query row.  Reads the row's 32
// pre-ranked winner keys (first 256 B of its own w row, written by
// logits_topk), computes e=exp(v-m) exactly as before (m = rank-0 = row
// max), renormalizes, then zero+scatter+NT-stream of the full w row and the
// 32-term weighted V sum.  No logits re-read, no threshold search.
// ---------------------------------------------------------------------------
__global__ __launch_bounds__(256)
void topk_scatter(float* __restrict__ wbuf, const float* __restrict__ Vh,
                  f16* __restrict__ attH, f16* __restrict__ attL)
{
    __shared__ float wrow[4][2048];
    __shared__ float win_w[4][TOPK];
    __shared__ int   win_i[4][TOPK];

    const int tid  = threadIdx.x;
    const int wv   = tid >> 6;
    const int lane = tid & 63;
    const int row  = blockIdx.x * 4 + wv;       // (b*8+h)*2048 + s
    float* wr = wbuf + (size_t)row * 2048;

    u64k key = 0;
    if (lane < TOPK) key = ((const u64k*)wr)[lane];
    unsigned sv = (unsigned)(key >> 16);
    unsigned fu = (sv & 0x80000000u) ? (sv ^ 0x80000000u) : ~sv;
    float v = __uint_as_float(fu);
    int idx = (int)(0xFFFFu - (unsigned)(key & 0xFFFFull)) & 2047;

    float m = __shfl(v, 0, 64);                 // rank-0 value = row max
    float e = (lane < TOPK) ? __expf(v - m) : 0.f;

    float mysum = e;
#pragma unroll
    for (int off = 32; off > 0; off >>= 1) mysum += __shfl_xor(mysum, off, 64);
    const float rw = 1.f / mysum;

    if (lane < TOPK) { win_w[wv][lane] = e; win_i[wv][lane] = idx; }

    const f32x4 z = {0.f, 0.f, 0.f, 0.f};
#pragma unroll
    for (int t = 0; t < 8; ++t) ((f32x4*)wrow[wv])[t * 64 + lane] = z;
    lds_fence();
    if (lane < TOPK) wrow[wv][win_i[wv][lane]] = win_w[wv][lane] * rw;
    lds_fence();

    // stream the sparse w row out (overwrites the winner-key scratch too)
#pragma unroll
    for (int t = 0; t < 8; ++t)
        __builtin_nontemporal_store(((f32x4*)wrow[wv])[t * 64 + lane],
                                    (f32x4*)(wr + (size_t)(t * 64 + lane) * 4));

    // sparse attention: 32 weighted V rows; lane = head-dim index
    const int bh = row >> 11;
    const float* Vb = Vh + (size_t)bh * S_LEN * DH;
    float acc = 0.f;
#pragma unroll
    for (int j = 0; j < TOPK; ++j) {
        float wj = win_w[wv][j] * rw;
        int   kj = win_i[wv][j];
        acc = fmaf(wj, Vb[(size_t)kj * DH + lane], acc);
    }
    const int b_ = row >> 14;
    const int h  = (row >> 11) & 7;
    const int s  = row & 2047;
    size_t oidx = (((size_t)b_ * S_LEN) + s) * 512 + h * DH + lane;
    f16 hh = (f16)acc;
    attH[oidx] = hh;
    attL[oidx] = (f16)((acc - (float)hh) * LO_SCALE);
}

// ---------------------------------------------------------------------------
extern "C" void kernel_launch(void* const* d_in, const int* in_sizes, int n_in,
                              void* d_out, int out_size, void* d_ws, size_t ws_size,
                              hipStream_t stream) {
    const float* v  = (const float*)d_in[0];
    const float* k  = (const float*)d_in[1];
    const float* q  = (const float*)d_in[2];
    const float* Wq = (const float*)d_in[3];
    const float* bq = (const float*)d_in[4];
    const float* Wk = (const float*)d_in[5];
    const float* bk = (const float*)d_in[6];
    const float* Wv = (const float*)d_in[7];
    const float* bv = (const float*)d_in[8];
    const float* Wo = (const float*)d_in[9];
    const float* bo = (const float*)d_in[10];

    float* out  = (float*)d_out;                    // [4,2048,512]
    float* wout = out + (size_t)4 * S_LEN * 512;    // [4,8,2048,2048] w output

    char* ws = (char*)d_ws;
    float* Vh   = (float*)ws;                       // fp32 [B,H,S,dh], 16 MB
    float* Qh32 = (float*)(ws + 16777216);          // fp32 [B,H,S,dh], 16 MB
    float* Kh32 = (float*)(ws + 33554432);          // fp32 [B,H,S,dh], 16 MB
    f16* WT  = (f16*)(ws + 50331648);               // 4 planes of 512x512, 2 MB
    f16 *WvH = WT,           *WvL = WT + 262144;
    f16 *WoH = WT + 524288,  *WoL = WT + 786432;
    // att planes alias Qh32 (dead after logits_topk): 8 MB + 8 MB
    f16* attH = (f16*)(ws + 16777216);
    f16* attL = (f16*)(ws + 25165824);

    wsplit2<<<dim3(16, 16, 2), 256, 0, stream>>>(Wv, Wo, WT);

    qkproj<<<dim3(4, 64, 2), 256, 0, stream>>>(q, k, Wq, Wk, bq, bk, Qh32, Kh32);
    gemm_x32<<<dim3(4, 64), 256, 0, stream>>>(v, WvH, WvL, bv, Vh, 1);

    logits_topk<<<dim3(32, 32), 256, 0, stream>>>(Qh32, Kh32, wout);

    topk_scatter<<<16384, 256, 0, stream>>>(wout, Vh, attH, attL);

    gemm_x16<<<dim3(4, 64, 1), 256, 0, stream>>>(attH, attL, WoH, WoL, bo, out, 512, 512, 2);
}